// Round 10
// baseline (328.017 us; speedup 1.0000x reference)
//
#include <hip/hip_runtime.h>

#define H 512
#define NNODES 10000
#define NEDGES 160000
#define NLAYERS 5
#define TM 160          // 63 M-tiles x 8 N-slices = 504 tiles -> 512 blocks = 2/CU, one round
#define NMT 63

typedef __attribute__((ext_vector_type(8))) short short8;
typedef __attribute__((ext_vector_type(4))) float floatx4;

// ---------- helpers ----------
__device__ inline unsigned short f2bf(float v) {
    union { float f; unsigned int u; } x; x.f = v;
    unsigned int r = (x.u + 0x7fffu + ((x.u >> 16) & 1u)) >> 16;
    return (unsigned short)r;
}
__device__ inline float bf2f(unsigned short u) {
    union { unsigned int u; float f; } x; x.u = ((unsigned int)u) << 16; return x.f;
}
__device__ inline void gl_lds16(const void* g, void* l) {
    __builtin_amdgcn_global_load_lds((const __attribute__((address_space(1))) void*)g,
                                     (__attribute__((address_space(3))) void*)l, 16, 0, 0);
}

// ---------- fused prep: [zero counts/fill | zero colsP/valsP | cvt feat | transpose W] ----------
// role decode by blockIdx.x; all parts independent.
#define PB_ZERO1 79      // 20000 ints
#define PB_ZERO2 1875    // 480000 ints (colsP+valsP pad slots)
#define PB_CVT   5000    // 1,280,000 float4 groups (NNODES*H/4)  [r9 bug: was 1250]
#define PB_TR    1536    // 6 x 256 transpose tiles
__global__ __launch_bounds__(256)
void fused_prep(int* __restrict__ counts, int* __restrict__ colsP,
                const float* __restrict__ feat, unsigned short* __restrict__ x,
                const float* __restrict__ Wg, const float* __restrict__ vw1,
                unsigned short* __restrict__ Wt) {
    const int b = blockIdx.x;
    const int t = threadIdx.x;
    if (b < PB_ZERO1) {
        int i = b * 256 + t;
        if (i < 20000) counts[i] = 0;
    } else if (b < PB_ZERO1 + PB_ZERO2) {
        int i = (b - PB_ZERO1) * 256 + t;
        if (i < 480000) colsP[i] = 0;
    } else if (b < PB_ZERO1 + PB_ZERO2 + PB_CVT) {
        int i = (b - PB_ZERO1 - PB_ZERO2) * 256 + t;
        if (i < NNODES * H / 4) {
            float4 v = ((const float4*)feat)[i];
            ushort4 o;
            o.x = f2bf(v.x); o.y = f2bf(v.y); o.z = f2bf(v.z); o.w = f2bf(v.w);
            ((ushort4*)x)[i] = o;
        }
    } else {
        __shared__ float tile[32][33];
        const int bb = b - PB_ZERO1 - PB_ZERO2 - PB_CVT;
        const int z = bb >> 8;            // 0..5
        const int rem = bb & 255;
        const int bx = (rem & 15) * 32;   // n base
        const int by = (rem >> 4) * 32;   // k base
        const float* in = (z < NLAYERS) ? (Wg + (size_t)z * H * H) : vw1;
        unsigned short* out = Wt + (size_t)z * H * H;
        const int tx = t & 31, ty = t >> 5;  // (32,8)
        for (int i = ty; i < 32; i += 8)
            tile[i][tx] = in[(size_t)(by + i) * H + bx + tx];
        __syncthreads();
        for (int i = ty; i < 32; i += 8)
            out[(size_t)(bx + i) * H + by + tx] = f2bf(tile[tx][i]);
    }
}

__global__ void edge_hist(const int* __restrict__ rows, int* __restrict__ counts, int n) {
    int i = blockIdx.x * blockDim.x + threadIdx.x;
    if (i < n) atomicAdd(&counts[rows[i]], 1);
}

// prefix-sum of row counts PADDED to multiples of 8 (dummy edges have val=0)
__global__ __launch_bounds__(1024)
void scan_rows_pad(const int* __restrict__ counts, int* __restrict__ row_ptr, int n) {
    __shared__ int sums[1024];
    const int t = threadIdx.x;
    const int base = t * 16;
    int local[16];
    int s = 0;
#pragma unroll
    for (int i = 0; i < 16; ++i) {
        int idx = base + i;
        int v = (idx < n) ? ((counts[idx] + 7) & ~7) : 0;
        local[i] = s;
        s += v;
    }
    sums[t] = s;
    __syncthreads();
    for (int off = 1; off < 1024; off <<= 1) {
        int v = (t >= off) ? sums[t - off] : 0;
        __syncthreads();
        sums[t] += v;
        __syncthreads();
    }
    const int prefix = (t == 0) ? 0 : sums[t - 1];
#pragma unroll
    for (int i = 0; i < 16; ++i) {
        int idx = base + i;
        if (idx < n) row_ptr[idx] = prefix + local[i];
    }
    if (t == 0) row_ptr[n] = sums[1023];
}

__global__ void edge_scatter(const int* __restrict__ rows, const int* __restrict__ colsin,
                             const float* __restrict__ valsin, const int* __restrict__ row_ptr,
                             int* __restrict__ fill, int* __restrict__ colsout,
                             float* __restrict__ valsout, int n) {
    int i = blockIdx.x * blockDim.x + threadIdx.x;
    if (i < n) {
        int r = rows[i];
        int pos = row_ptr[r] + atomicAdd(&fill[r], 1);
        colsout[pos] = colsin[i];
        valsout[pos] = valsin[i];
    }
}

// ---------- GEMM: TM=160 x TN=64, BK=64, XOR k-slot swizzle, XCD-aware decode ----------
// 512 blocks (8 no-op) = exactly 2/CU, single dispatch round. Same per-element
// MFMA K-chain as r3/r8 -> bit-identical numerics.
__global__ __launch_bounds__(256)
void gemm_bf16_160(const unsigned short* __restrict__ A, const unsigned short* __restrict__ Bt,
                   unsigned short* __restrict__ C, const float* __restrict__ bias,
                   int has_bias_relu, int M) {
    __shared__ __align__(16) unsigned short lsA[TM * 64];  // 20 KB
    __shared__ __align__(16) unsigned short lsB[64 * 64];  //  8 KB
    // XCD decode: 8 N-slices of an M-tile share L%8 -> same XCD -> A reused in L2
    const int L = blockIdx.x;
    const int ml = L & 7;
    const int rest = L >> 3;
    const int n = rest & 7;
    const int mh = rest >> 3;
    const int m = mh * 8 + ml;
    if (m >= NMT) return;
    const int tileM = m * TM;
    const int tileN = n * 64;

    const int t = threadIdx.x;
    const int lane = t & 63;
    const int wave = t >> 6;
    const int wm = wave >> 1, wn = wave & 1;   // wm: 80-row half, wn: 32-col half
    const int quad = lane >> 4, r16 = lane & 15;

    floatx4 acc[5][2] = {};

    // A staging: 1280 chunks of 16B (row = c>>3, k-slot = (c&7)^(row&7))
    const unsigned short* ap[5];
#pragma unroll
    for (int q = 0; q < 5; ++q) {
        const int c = t + 256 * q;
        const int row = c >> 3;
        int g = tileM + row; if (g >= M) g = M - 1;
        ap[q] = A + (size_t)g * 512 + (((c & 7) ^ (row & 7)) * 8);
    }
    const unsigned short* bp[2];
#pragma unroll
    for (int q = 0; q < 2; ++q) {
        const int c = t + 256 * q;
        const int row = c >> 3;
        bp[q] = Bt + (size_t)(tileN + row) * 512 + (((c & 7) ^ (row & 7)) * 8);
    }

    for (int k0 = 0; k0 < 512; k0 += 64) {
#pragma unroll
        for (int q = 0; q < 5; ++q)
            gl_lds16(ap[q] + k0, lsA + (size_t)(t + 256 * q) * 8);
        gl_lds16(bp[0] + k0, lsB + (size_t)t * 8);
        gl_lds16(bp[1] + k0, lsB + (size_t)(t + 256) * 8);
        __syncthreads();

        short8 af[5][2], bfr[2][2];
#pragma unroll
        for (int i = 0; i < 5; ++i) {
            const int row = wm * 80 + i * 16 + r16;
#pragma unroll
            for (int kk = 0; kk < 2; ++kk) {
                const int kcw = kk * 4 + quad;
                af[i][kk] = *(const short8*)&lsA[(size_t)(row * 8 + (kcw ^ (row & 7))) * 8];
            }
        }
#pragma unroll
        for (int j = 0; j < 2; ++j) {
            const int row = wn * 32 + j * 16 + r16;
#pragma unroll
            for (int kk = 0; kk < 2; ++kk) {
                const int kcw = kk * 4 + quad;
                bfr[j][kk] = *(const short8*)&lsB[(size_t)(row * 8 + (kcw ^ (row & 7))) * 8];
            }
        }
#pragma unroll
        for (int kk = 0; kk < 2; ++kk)  // K ascending -> numerics match r8 exactly
#pragma unroll
            for (int i = 0; i < 5; ++i)
#pragma unroll
                for (int j = 0; j < 2; ++j)
                    acc[i][j] = __builtin_amdgcn_mfma_f32_16x16x32_bf16(af[i][kk], bfr[j][kk], acc[i][j], 0, 0, 0);
        __syncthreads();
    }

    // epilogue: C/D map col=lane&15, row=(lane>>4)*4+reg
#pragma unroll
    for (int i = 0; i < 5; ++i) {
#pragma unroll
        for (int j = 0; j < 2; ++j) {
            const int col = tileN + wn * 32 + j * 16 + r16;
#pragma unroll
            for (int reg = 0; reg < 4; ++reg) {
                const int row = tileM + wm * 80 + i * 16 + quad * 4 + reg;
                if (row < M) {
                    float v = acc[i][j][reg];
                    if (has_bias_relu) { v += bias[col]; v = fmaxf(v, 0.f); }
                    C[(size_t)row * 512 + col] = f2bf(v);
                }
            }
        }
    }
}

// ---------- SpMM + bias + relu on padded CSR: branch-free unroll-8 rounds ----------
__global__ __launch_bounds__(256)
void spmm_pad(const int* __restrict__ prow, const int* __restrict__ cols,
              const float* __restrict__ vals, const unsigned short* __restrict__ hmat,
              const float* __restrict__ bias, unsigned short* __restrict__ xout) {
    const int wave = threadIdx.x >> 6, lane = threadIdx.x & 63;
    const int r = blockIdx.x * 4 + wave;
    if (r >= NNODES) return;
    const int s = prow[r], e = prow[r + 1];  // multiple of 8
    const int cb = lane * 8;
    float acc[8] = {0.f, 0.f, 0.f, 0.f, 0.f, 0.f, 0.f, 0.f};

    for (int i = s; i < e; i += 8) {
        int c[8]; float v[8]; short8 g[8];
#pragma unroll
        for (int u = 0; u < 8; ++u) { c[u] = cols[i + u]; v[u] = vals[i + u]; }
#pragma unroll
        for (int u = 0; u < 8; ++u) g[u] = *(const short8*)(hmat + (size_t)c[u] * H + cb);
#pragma unroll
        for (int u = 0; u < 8; ++u)  // real-edge order preserved; pads are exact +0
#pragma unroll
            for (int j = 0; j < 8; ++j) acc[j] += v[u] * bf2f((unsigned short)g[u][j]);
    }

    short8 o;
#pragma unroll
    for (int j = 0; j < 8; ++j)
        o[j] = (short)f2bf(fmaxf(acc[j] + bias[cb + j], 0.f));
    *(short8*)(xout + (size_t)r * H + cb) = o;
}

// ---------- head: out[r] = sigmoid(dot(h2[r,:], w2) + b2) ----------
__global__ __launch_bounds__(256)
void final_head(const unsigned short* __restrict__ h2, const float* __restrict__ w2,
                const float* __restrict__ b2, float* __restrict__ out, int n) {
    const int wave = threadIdx.x >> 6, lane = threadIdx.x & 63;
    const int r = blockIdx.x * 4 + wave;
    if (r >= n) return;
    const unsigned short* hrow = h2 + (size_t)r * H;
    float acc = 0.f;
#pragma unroll
    for (int i = 0; i < 8; ++i) {
        const int c = lane * 8 + i;
        acc += bf2f(hrow[c]) * w2[c];
    }
#pragma unroll
    for (int off = 32; off >= 1; off >>= 1) acc += __shfl_xor(acc, off, 64);
    if (lane == 0) out[r] = 1.f / (1.f + expf(-(acc + b2[0])));
}

extern "C" void kernel_launch(void* const* d_in, const int* in_sizes, int n_in,
                              void* d_out, int out_size, void* d_ws, size_t ws_size,
                              hipStream_t stream) {
    (void)in_sizes; (void)n_in; (void)out_size; (void)ws_size;
    const float* feat   = (const float*)d_in[0];
    const int* adj_row  = (const int*)d_in[1];
    const int* adj_col  = (const int*)d_in[2];
    const float* adj_val= (const float*)d_in[3];
    const float* Wg     = (const float*)d_in[4];
    const float* bg     = (const float*)d_in[5];
    const float* vw1    = (const float*)d_in[6];
    const float* vb1    = (const float*)d_in[7];
    const float* vw2    = (const float*)d_in[8];
    const float* vb2    = (const float*)d_in[9];
    float* out = (float*)d_out;

    // workspace layout (bytes)
    char* ws = (char*)d_ws;
    unsigned short* x  = (unsigned short*)(ws + 0);          // 10,240,000
    unsigned short* h  = (unsigned short*)(ws + 10240000);   // 10,240,000
    unsigned short* Wt = (unsigned short*)(ws + 20480000);   // 3,145,728
    int*   prow    = (int*)(ws + 23625728);                  // 160,064
    int*   counts  = (int*)(ws + 23785792);                  // 40,000
    int*   fill    = (int*)(ws + 23825792);                  // 40,000 (contiguous after counts)
    int*   colsP   = (int*)(ws + 23865792);                  // 960,000 (240k padded edges)
    float* valsP   = (float*)(ws + 24825792);                // 960,000 -> ~25.8 MB

    // --- prep (fused independent parts, then CSR chain) ---
    fused_prep<<<PB_ZERO1 + PB_ZERO2 + PB_CVT + PB_TR, 256, 0, stream>>>(
        counts, colsP, feat, x, Wg, vw1, Wt);
    edge_hist<<<(NEDGES + 255) / 256, 256, 0, stream>>>(adj_row, counts, NEDGES);
    scan_rows_pad<<<1, 1024, 0, stream>>>(counts, prow, NNODES);
    edge_scatter<<<(NEDGES + 255) / 256, 256, 0, stream>>>(adj_row, adj_col, adj_val,
                                                           prow, fill, colsP, valsP, NEDGES);

    // --- layers ---
    for (int l = 0; l < NLAYERS; ++l) {
        gemm_bf16_160<<<512, 256, 0, stream>>>(x, Wt + (size_t)l * H * H, h, nullptr, 0, NNODES);
        spmm_pad<<<(NNODES + 3) / 4, 256, 0, stream>>>(prow, colsP, valsP, h, bg + (size_t)l * H, x);
    }
    gemm_bf16_160<<<512, 256, 0, stream>>>(x, Wt + (size_t)NLAYERS * H * H, h, vb1, 1, NNODES);
    final_head<<<(NNODES + 3) / 4, 256, 0, stream>>>(h, vw2, vb2, out, NNODES);
}

// Round 11
// 326.732 us; speedup vs baseline: 1.0039x; 1.0039x over previous
//
#include <hip/hip_runtime.h>

#define H 512
#define NNODES 10000
#define NEDGES 160000
#define NLAYERS 5
#define TM 160          // 63 M-tiles x 8 N-slices = 504 tiles -> 512 blocks = 2/CU, one round
#define NMT 63
#define HISTB 625       // hist blocks piggybacked on GEMM-1

typedef __attribute__((ext_vector_type(8))) short short8;
typedef __attribute__((ext_vector_type(4))) float floatx4;

// ---------- helpers ----------
__device__ inline unsigned short f2bf(float v) {
    union { float f; unsigned int u; } x; x.f = v;
    unsigned int r = (x.u + 0x7fffu + ((x.u >> 16) & 1u)) >> 16;
    return (unsigned short)r;
}
__device__ inline float bf2f(unsigned short u) {
    union { unsigned int u; float f; } x; x.u = ((unsigned int)u) << 16; return x.f;
}
__device__ inline void gl_lds16(const void* g, void* l) {
    __builtin_amdgcn_global_load_lds((const __attribute__((address_space(1))) void*)g,
                                     (__attribute__((address_space(3))) void*)l, 16, 0, 0);
}

// ---------- fused prep: [zero counts/fill | zero colsP/valsP | cvt feat | transpose W] ----------
#define PB_ZERO1 79      // 20000 ints
#define PB_ZERO2 1875    // 480000 ints (colsP+valsP pad slots)
#define PB_CVT   5000    // 1,280,000 float4 groups (NNODES*H/4)
#define PB_TR    1536    // 6 x 256 transpose tiles
__global__ __launch_bounds__(256)
void fused_prep(int* __restrict__ counts, int* __restrict__ colsP,
                const float* __restrict__ feat, unsigned short* __restrict__ x,
                const float* __restrict__ Wg, const float* __restrict__ vw1,
                unsigned short* __restrict__ Wt) {
    const int b = blockIdx.x;
    const int t = threadIdx.x;
    if (b < PB_ZERO1) {
        int i = b * 256 + t;
        if (i < 20000) counts[i] = 0;
    } else if (b < PB_ZERO1 + PB_ZERO2) {
        int i = (b - PB_ZERO1) * 256 + t;
        if (i < 480000) colsP[i] = 0;
    } else if (b < PB_ZERO1 + PB_ZERO2 + PB_CVT) {
        int i = (b - PB_ZERO1 - PB_ZERO2) * 256 + t;
        if (i < NNODES * H / 4) {
            float4 v = ((const float4*)feat)[i];
            ushort4 o;
            o.x = f2bf(v.x); o.y = f2bf(v.y); o.z = f2bf(v.z); o.w = f2bf(v.w);
            ((ushort4*)x)[i] = o;
        }
    } else {
        __shared__ float tile[32][33];
        const int bb = b - PB_ZERO1 - PB_ZERO2 - PB_CVT;
        const int z = bb >> 8;            // 0..5
        const int rem = bb & 255;
        const int bx = (rem & 15) * 32;   // n base
        const int by = (rem >> 4) * 32;   // k base
        const float* in = (z < NLAYERS) ? (Wg + (size_t)z * H * H) : vw1;
        unsigned short* out = Wt + (size_t)z * H * H;
        const int tx = t & 31, ty = t >> 5;  // (32,8)
        for (int i = ty; i < 32; i += 8)
            tile[i][tx] = in[(size_t)(by + i) * H + bx + tx];
        __syncthreads();
        for (int i = ty; i < 32; i += 8)
            out[(size_t)(bx + i) * H + by + tx] = f2bf(tile[tx][i]);
    }
}

// prefix-sum of row counts PADDED to multiples of 8 (dummy edges have val=0)
__global__ __launch_bounds__(1024)
void scan_rows_pad(const int* __restrict__ counts, int* __restrict__ row_ptr, int n) {
    __shared__ int sums[1024];
    const int t = threadIdx.x;
    const int base = t * 16;
    int local[16];
    int s = 0;
#pragma unroll
    for (int i = 0; i < 16; ++i) {
        int idx = base + i;
        int v = (idx < n) ? ((counts[idx] + 7) & ~7) : 0;
        local[i] = s;
        s += v;
    }
    sums[t] = s;
    __syncthreads();
    for (int off = 1; off < 1024; off <<= 1) {
        int v = (t >= off) ? sums[t - off] : 0;
        __syncthreads();
        sums[t] += v;
        __syncthreads();
    }
    const int prefix = (t == 0) ? 0 : sums[t - 1];
#pragma unroll
    for (int i = 0; i < 16; ++i) {
        int idx = base + i;
        if (idx < n) row_ptr[idx] = prefix + local[i];
    }
    if (t == 0) row_ptr[n] = sums[1023];
}

__global__ void edge_scatter(const int* __restrict__ rows, const int* __restrict__ colsin,
                             const float* __restrict__ valsin, const int* __restrict__ row_ptr,
                             int* __restrict__ fill, int* __restrict__ colsout,
                             float* __restrict__ valsout, int n) {
    int i = blockIdx.x * blockDim.x + threadIdx.x;
    if (i < n) {
        int r = rows[i];
        int pos = row_ptr[r] + atomicAdd(&fill[r], 1);
        colsout[pos] = colsin[i];
        valsout[pos] = valsin[i];
    }
}

// ---------- GEMM: TM=160 x TN=64, BK=64, XOR k-slot swizzle, XCD-aware decode ----------
// Blocks >= 512 (first launch only) run the edge histogram instead (piggyback:
// needs counts zeroed in prep; no ordering vs GEMM blocks required).
__global__ __launch_bounds__(256)
void gemm_bf16_160h(const unsigned short* __restrict__ A, const unsigned short* __restrict__ Bt,
                    unsigned short* __restrict__ C, const float* __restrict__ bias,
                    int has_bias_relu, int M,
                    const int* __restrict__ hrows, int* __restrict__ hcounts) {
    if (blockIdx.x >= 512) {
        const int i = (blockIdx.x - 512) * 256 + threadIdx.x;
        if (i < NEDGES) atomicAdd(&hcounts[hrows[i]], 1);
        return;
    }
    __shared__ __align__(16) unsigned short lsA[TM * 64];  // 20 KB
    __shared__ __align__(16) unsigned short lsB[64 * 64];  //  8 KB
    // XCD decode: 8 N-slices of an M-tile share L%8 -> same XCD -> A reused in L2
    const int L = blockIdx.x;
    const int ml = L & 7;
    const int rest = L >> 3;
    const int n = rest & 7;
    const int mh = rest >> 3;
    const int m = mh * 8 + ml;
    if (m >= NMT) return;
    const int tileM = m * TM;
    const int tileN = n * 64;

    const int t = threadIdx.x;
    const int lane = t & 63;
    const int wave = t >> 6;
    const int wm = wave >> 1, wn = wave & 1;   // wm: 80-row half, wn: 32-col half
    const int quad = lane >> 4, r16 = lane & 15;

    floatx4 acc[5][2] = {};

    const unsigned short* ap[5];
#pragma unroll
    for (int q = 0; q < 5; ++q) {
        const int c = t + 256 * q;
        const int row = c >> 3;
        int g = tileM + row; if (g >= M) g = M - 1;
        ap[q] = A + (size_t)g * 512 + (((c & 7) ^ (row & 7)) * 8);
    }
    const unsigned short* bp[2];
#pragma unroll
    for (int q = 0; q < 2; ++q) {
        const int c = t + 256 * q;
        const int row = c >> 3;
        bp[q] = Bt + (size_t)(tileN + row) * 512 + (((c & 7) ^ (row & 7)) * 8);
    }

    for (int k0 = 0; k0 < 512; k0 += 64) {
#pragma unroll
        for (int q = 0; q < 5; ++q)
            gl_lds16(ap[q] + k0, lsA + (size_t)(t + 256 * q) * 8);
        gl_lds16(bp[0] + k0, lsB + (size_t)t * 8);
        gl_lds16(bp[1] + k0, lsB + (size_t)(t + 256) * 8);
        __syncthreads();

        short8 af[5][2], bfr[2][2];
#pragma unroll
        for (int i = 0; i < 5; ++i) {
            const int row = wm * 80 + i * 16 + r16;
#pragma unroll
            for (int kk = 0; kk < 2; ++kk) {
                const int kcw = kk * 4 + quad;
                af[i][kk] = *(const short8*)&lsA[(size_t)(row * 8 + (kcw ^ (row & 7))) * 8];
            }
        }
#pragma unroll
        for (int j = 0; j < 2; ++j) {
            const int row = wn * 32 + j * 16 + r16;
#pragma unroll
            for (int kk = 0; kk < 2; ++kk) {
                const int kcw = kk * 4 + quad;
                bfr[j][kk] = *(const short8*)&lsB[(size_t)(row * 8 + (kcw ^ (row & 7))) * 8];
            }
        }
#pragma unroll
        for (int kk = 0; kk < 2; ++kk)  // K ascending -> numerics match r10 exactly
#pragma unroll
            for (int i = 0; i < 5; ++i)
#pragma unroll
                for (int j = 0; j < 2; ++j)
                    acc[i][j] = __builtin_amdgcn_mfma_f32_16x16x32_bf16(af[i][kk], bfr[j][kk], acc[i][j], 0, 0, 0);
        __syncthreads();
    }

    // epilogue: C/D map col=lane&15, row=(lane>>4)*4+reg
#pragma unroll
    for (int i = 0; i < 5; ++i) {
#pragma unroll
        for (int j = 0; j < 2; ++j) {
            const int col = tileN + wn * 32 + j * 16 + r16;
#pragma unroll
            for (int reg = 0; reg < 4; ++reg) {
                const int row = tileM + wm * 80 + i * 16 + quad * 4 + reg;
                if (row < M) {
                    float v = acc[i][j][reg];
                    if (has_bias_relu) { v += bias[col]; v = fmaxf(v, 0.f); }
                    C[(size_t)row * 512 + col] = f2bf(v);
                }
            }
        }
    }
}

// ---------- SpMM split-edge: 2 waves per row (half the serial chain depth), ----------
// LDS pairwise reduce. Block = 256 thr = 4 waves = 2 rows; grid 5000 (exact).
__global__ __launch_bounds__(256)
void spmm_split(const int* __restrict__ prow, const int* __restrict__ cols,
                const float* __restrict__ vals, const unsigned short* __restrict__ hmat,
                const float* __restrict__ bias, unsigned short* __restrict__ xout) {
    __shared__ float red[2][64][8];  // 4 KB
    const int wave = threadIdx.x >> 6, lane = threadIdx.x & 63;
    const int rowIdx = wave >> 1;    // 0..1
    const int half = wave & 1;       // 0 = first edge-half, 1 = second
    const int r = blockIdx.x * 2 + rowIdx;   // always < 10000 (grid exact)
    const int cb = lane * 8;

    const int s0 = prow[r], e0 = prow[r + 1];       // padded length, multiple of 8
    const int nr = (e0 - s0) >> 3;                  // unroll-8 rounds
    const int ra = (nr + 1) >> 1;                   // rounds for half 0
    const int s = half ? (s0 + ra * 8) : s0;
    const int e = half ? e0 : (s0 + ra * 8);

    float acc[8] = {0.f, 0.f, 0.f, 0.f, 0.f, 0.f, 0.f, 0.f};
    for (int i = s; i < e; i += 8) {
        int c[8]; float v[8]; short8 g[8];
#pragma unroll
        for (int u = 0; u < 8; ++u) { c[u] = cols[i + u]; v[u] = vals[i + u]; }
#pragma unroll
        for (int u = 0; u < 8; ++u) g[u] = *(const short8*)(hmat + (size_t)c[u] * H + cb);
#pragma unroll
        for (int u = 0; u < 8; ++u)  // in-half edge order preserved; pads exact +0
#pragma unroll
            for (int j = 0; j < 8; ++j) acc[j] += v[u] * bf2f((unsigned short)g[u][j]);
    }

    if (half == 1) {
#pragma unroll
        for (int j = 0; j < 8; ++j) red[rowIdx][lane][j] = acc[j];
    }
    __syncthreads();
    if (half == 0) {
        short8 o;
#pragma unroll
        for (int j = 0; j < 8; ++j) {
            float v = acc[j] + red[rowIdx][lane][j] + bias[cb + j];
            o[j] = (short)f2bf(fmaxf(v, 0.f));
        }
        *(short8*)(xout + (size_t)r * H + cb) = o;
    }
}

// ---------- head: out[r] = sigmoid(dot(h2[r,:], w2) + b2) ----------
__global__ __launch_bounds__(256)
void final_head(const unsigned short* __restrict__ h2, const float* __restrict__ w2,
                const float* __restrict__ b2, float* __restrict__ out, int n) {
    const int wave = threadIdx.x >> 6, lane = threadIdx.x & 63;
    const int r = blockIdx.x * 4 + wave;
    if (r >= n) return;
    const unsigned short* hrow = h2 + (size_t)r * H;
    float acc = 0.f;
#pragma unroll
    for (int i = 0; i < 8; ++i) {
        const int c = lane * 8 + i;
        acc += bf2f(hrow[c]) * w2[c];
    }
#pragma unroll
    for (int off = 32; off >= 1; off >>= 1) acc += __shfl_xor(acc, off, 64);
    if (lane == 0) out[r] = 1.f / (1.f + expf(-(acc + b2[0])));
}

extern "C" void kernel_launch(void* const* d_in, const int* in_sizes, int n_in,
                              void* d_out, int out_size, void* d_ws, size_t ws_size,
                              hipStream_t stream) {
    (void)in_sizes; (void)n_in; (void)out_size; (void)ws_size;
    const float* feat   = (const float*)d_in[0];
    const int* adj_row  = (const int*)d_in[1];
    const int* adj_col  = (const int*)d_in[2];
    const float* adj_val= (const float*)d_in[3];
    const float* Wg     = (const float*)d_in[4];
    const float* bg     = (const float*)d_in[5];
    const float* vw1    = (const float*)d_in[6];
    const float* vb1    = (const float*)d_in[7];
    const float* vw2    = (const float*)d_in[8];
    const float* vb2    = (const float*)d_in[9];
    float* out = (float*)d_out;

    // workspace layout (bytes)
    char* ws = (char*)d_ws;
    unsigned short* x  = (unsigned short*)(ws + 0);          // 10,240,000
    unsigned short* h  = (unsigned short*)(ws + 10240000);   // 10,240,000
    unsigned short* Wt = (unsigned short*)(ws + 20480000);   // 3,145,728
    int*   prow    = (int*)(ws + 23625728);                  // 160,064
    int*   counts  = (int*)(ws + 23785792);                  // 40,000
    int*   fill    = (int*)(ws + 23825792);                  // 40,000 (contiguous after counts)
    int*   colsP   = (int*)(ws + 23865792);                  // 960,000 (240k padded edges)
    float* valsP   = (float*)(ws + 24825792);                // 960,000 -> ~25.8 MB

    // --- prep: zeros + cvt + transpose (independent parts) ---
    fused_prep<<<PB_ZERO1 + PB_ZERO2 + PB_CVT + PB_TR, 256, 0, stream>>>(
        counts, colsP, feat, x, Wg, vw1, Wt);

    // --- GEMM layer 0 with edge_hist piggybacked on blocks [512, 1137) ---
    gemm_bf16_160h<<<512 + HISTB, 256, 0, stream>>>(x, Wt, h, nullptr, 0, NNODES,
                                                    adj_row, counts);
    scan_rows_pad<<<1, 1024, 0, stream>>>(counts, prow, NNODES);
    edge_scatter<<<(NEDGES + 255) / 256, 256, 0, stream>>>(adj_row, adj_col, adj_val,
                                                           prow, fill, colsP, valsP, NEDGES);
    spmm_split<<<NNODES / 2, 256, 0, stream>>>(prow, colsP, valsP, h, bg, x);

    // --- layers 1..4 ---
    for (int l = 1; l < NLAYERS; ++l) {
        gemm_bf16_160h<<<512, 256, 0, stream>>>(x, Wt + (size_t)l * H * H, h, nullptr, 0,
                                                NNODES, adj_row, counts);
        spmm_split<<<NNODES / 2, 256, 0, stream>>>(prow, colsP, valsP, h,
                                                   bg + (size_t)l * H, x);
    }
    // --- final GEMM (bias+relu) + head ---
    gemm_bf16_160h<<<512, 256, 0, stream>>>(x, Wt + (size_t)NLAYERS * H * H, h, vb1, 1,
                                            NNODES, adj_row, counts);
    final_head<<<(NNODES + 3) / 4, 256, 0, stream>>>(h, vw2, vb2, out, NNODES);
}